// Round 20
// baseline (580.854 us; speedup 1.0000x reference)
//
#include <hip/hip_runtime.h>
#include <hip/hip_bf16.h>
#include <math.h>

constexpr int D = 128;
constexpr float EPS = 1e-5f;
constexpr float BETA = 0.9f;
constexpr int CAP = 64;        // global bucket row stride (ints)
constexpr int LCAP = 48;       // LDS bucket capacity (max in-degree ~45)
constexpr int KV_BLOCKS = 96;  // kv partial count (grid-stride)
constexpr int BIN_SHIFT = 8;   // 256 nodes per dst-bin
constexpr int BIN_CAPACITY = 5120;   // edges per bin region (mean 4096, +16 sigma slack)

typedef __attribute__((ext_vector_type(8))) short bf16x8;
typedef __attribute__((ext_vector_type(4))) float f32x4;

__device__ __forceinline__ float wave_allreduce_sum(float v) {
#pragma unroll
    for (int off = 32; off > 0; off >>= 1)
        v += __shfl_xor(v, off, 64);
    return v;
}

__device__ __forceinline__ ushort f2bf(float f) {
    union { float f; unsigned u; } v; v.f = f;
    unsigned r = v.u + 0x7FFFu + ((v.u >> 16) & 1u);   // RN-even
    return (ushort)(r >> 16);
}
__device__ __forceinline__ float bf2f(ushort u) {
    union { unsigned u; float f; } v; v.u = ((unsigned)u) << 16; return v.f;
}
__device__ __forceinline__ unsigned packbf(float a, float b) {
    return (unsigned)f2bf(a) | ((unsigned)f2bf(b) << 16);
}

template <int ACT> __device__ __forceinline__ float apply_act(float v) {
    if constexpr (ACT == 1) return fmaxf(v, 0.f);
    else if constexpr (ACT == 2) return 1.f / (1.f + expf(-v));
    else return v;
}

// ================= weight transpose+convert: W[k][n] f32 -> Wt[n][k] bf16 ==========
struct WP { const float* p[10]; };

__device__ __forceinline__ void transpose_tile_body(
    const float* __restrict__ src, ushort* __restrict__ d, float (*t)[33])
{
    int tr = (blockIdx.x >> 2) * 32, tc = (blockIdx.x & 3) * 32;
    int lr = threadIdx.x >> 5;
    int lc = threadIdx.x & 31;
#pragma unroll
    for (int i = 0; i < 4; ++i)
        t[lr + 8 * i][lc] = src[(size_t)(tr + lr + 8 * i) * D + tc + lc];
    __syncthreads();
#pragma unroll
    for (int i = 0; i < 4; ++i) {
        int r = lr + 8 * i;
        d[(size_t)(tc + r) * D + tr + lc] = f2bf(t[lc][r]);
    }
}

__global__ __launch_bounds__(256) void transpose_convert10(WP wp, ushort* __restrict__ dst) {
    __shared__ float t[32][33];
    transpose_tile_body(wp.p[blockIdx.y], dst + (size_t)blockIdx.y * D * D, t);
}

__global__ void transpose_pred(const float* __restrict__ w, ushort* __restrict__ wt) {
    int idx = blockIdx.x * 256 + threadIdx.x;   // 40*128
    if (idx < 40 * 128) {
        int n = idx >> 7, k = idx & 127;
        wt[idx] = f2bf(w[(size_t)k * 40 + n]);
    }
}

// ================= binned edge scatter (R16-validated) =================
__global__ __launch_bounds__(256) void bin_edges(
    const int* __restrict__ esrc, const int* __restrict__ edst, int E, int nbins,
    int* __restrict__ binCursor, int2* __restrict__ binned)
{
    __shared__ int hist[512];
    __shared__ int base[512];
    const int tid = threadIdx.x;
    const int per = (E + gridDim.x - 1) / gridDim.x;
    const int e0 = blockIdx.x * per;
    const int e1 = min(e0 + per, E);
    for (int i = tid; i < nbins; i += 256) hist[i] = 0;
    __syncthreads();
    for (int e = e0 + tid; e < e1; e += 256)
        atomicAdd(&hist[edst[e] >> BIN_SHIFT], 1);
    __syncthreads();
    for (int i = tid; i < nbins; i += 256)
        base[i] = hist[i] ? atomicAdd(&binCursor[i], hist[i]) : 0;
    __syncthreads();
    for (int i = tid; i < nbins; i += 256) hist[i] = 0;   // reuse as running cursor
    __syncthreads();
    for (int e = e0 + tid; e < e1; e += 256) {
        int d = edst[e];
        int b = d >> BIN_SHIFT;
        int slot = base[b] + atomicAdd(&hist[b], 1);
        if (slot < BIN_CAPACITY)
            binned[(size_t)b * BIN_CAPACITY + slot] = make_int2(esrc[e], d);
    }
}

// Pass C: buckets assembled in LDS; streaming emit; also writes cnt and dinv.
__global__ __launch_bounds__(256, 2) void bucket_from_bins_lds(
    const int2* __restrict__ binned, const int* __restrict__ binCursor, int N,
    int* __restrict__ cur, float* __restrict__ dinv, int* __restrict__ bucket)
{
    __shared__ int lcnt[256];
    __shared__ int lbuck[256 * LCAP];
    const int b = blockIdx.x;
    const int tid = threadIdx.x;
    const int node0 = b << BIN_SHIFT;
    lcnt[tid] = 0;
    __syncthreads();
    int cnt = binCursor[b];
    if (cnt > BIN_CAPACITY) cnt = BIN_CAPACITY;
    const int2* src = binned + (size_t)b * BIN_CAPACITY;
    for (int i = tid; i < cnt; i += 256) {
        int2 e = src[i];
        int ln = e.y - node0;                  // 0..255
        int pos = atomicAdd(&lcnt[ln], 1);
        if (pos < LCAP) lbuck[ln * LCAP + pos] = e.x;
    }
    __syncthreads();
    int node = node0 + tid;
    if (node < N) {
        cur[node] = lcnt[tid];                 // raw degree
        dinv[node] = rsqrtf((float)(lcnt[tid] + 1));
    }
    for (int i = tid; i < 256 * CAP; i += 256) {
        int ln = i >> 6, slot = i & 63;
        int gnode = node0 + ln;
        if (gnode < N && slot < LCAP) {
            int c = lcnt[ln]; if (c > LCAP) c = LCAP;
            int lim = (c + 15) & ~15;          // whole 64B lines
            if (slot < lim)
                bucket[(size_t)gnode * CAP + slot] = lbuck[ln * LCAP + slot];
        }
    }
}

// ================= shared MFMA GEMM pieces =================
// 512-thread (8-wave) variants — wave w owns rows w*16..w*16+15
__device__ __forceinline__ void stage_x_f32_512(ushort (*Xs)[136], const float* __restrict__ X,
                                                int row0, int N, int tid) {
#pragma unroll
    for (int p = 0; p < 8; ++p) {
        int idx = p * 512 + tid;
        int r = idx >> 5, c4 = idx & 31;
        int rg = row0 + r;
        float4 v = make_float4(0.f, 0.f, 0.f, 0.f);
        if (rg < N) v = *reinterpret_cast<const float4*>(X + (size_t)rg * D + c4 * 4);
        ushort4 o; o.x = f2bf(v.x); o.y = f2bf(v.y); o.z = f2bf(v.z); o.w = f2bf(v.w);
        *reinterpret_cast<ushort4*>(&Xs[r][c4 * 4]) = o;
    }
}

__device__ __forceinline__ void stage_x_bf16_512(ushort (*Xs)[136], const ushort* __restrict__ X,
                                                 int row0, int N, int tid) {
#pragma unroll
    for (int p = 0; p < 4; ++p) {
        int idx = p * 512 + tid;
        int r = idx >> 4, c = idx & 15;
        int rg = row0 + r;
        ulonglong2 v = {0ull, 0ull};
        if (rg < N) v = *reinterpret_cast<const ulonglong2*>(X + (size_t)rg * D + c * 8);
        *reinterpret_cast<ulonglong2*>(&Xs[r][c * 8]) = v;
    }
}

__device__ __forceinline__ void stage_w_512(ushort (*Ws)[136], const ushort* __restrict__ Wt, int tid) {
#pragma unroll
    for (int p = 0; p < 4; ++p) {
        int idx = p * 512 + tid;
        int r = idx >> 4, c = idx & 15;
        *reinterpret_cast<ulonglong2*>(&Ws[r][c * 8]) =
            *reinterpret_cast<const ulonglong2*>(Wt + (size_t)r * D + c * 8);
    }
}

__device__ __forceinline__ void mfma_core_512(const ushort (*Xs)[136], const ushort (*Ws)[136],
                                              f32x4 (&acc)[8], int w, int lr, int g) {
#pragma unroll
    for (int ks = 0; ks < 4; ++ks) {
        bf16x8 a0 = *reinterpret_cast<const bf16x8*>(&Xs[w * 16 + lr][ks * 32 + g * 8]);
#pragma unroll
        for (int cf = 0; cf < 8; ++cf) {
            bf16x8 bfr = *reinterpret_cast<const bf16x8*>(&Ws[cf * 16 + lr][ks * 32 + g * 8]);
            acc[cf] = __builtin_amdgcn_mfma_f32_16x16x32_bf16(a0, bfr, acc[cf], 0, 0, 0);
        }
    }
}

template <int ACT>
__device__ __forceinline__ void store_bf16_512(ushort* __restrict__ Y, const f32x4 (&acc)[8],
    const float* __restrict__ bias, int row0, int w, int lr, int g, int N) {
#pragma unroll
    for (int cf = 0; cf < 8; ++cf) {
        int col = cf * 16 + lr;
        float bb = bias ? bias[col] : 0.f;
        int rg0 = row0 + w * 16 + g * 4;
        if (rg0 < N) {           // N%4==0: whole 4-row group valid when rg0<N
#pragma unroll
            for (int j = 0; j < 4; ++j)
                Y[(size_t)(rg0 + j) * D + col] = f2bf(apply_act<ACT>(acc[cf][j] + bb));
        }
    }
}

// ---- stage1 triple (pure GEMM, 8-wave) ----
__global__ __launch_bounds__(512, 2) void k_triple1(
    const float* __restrict__ X, const ushort* __restrict__ W0, const ushort* __restrict__ W1,
    const ushort* __restrict__ W2, const float* __restrict__ b0, const float* __restrict__ b2,
    ushort* __restrict__ Y0, ushort* __restrict__ Y1, ushort* __restrict__ Y2, int N)
{
    __shared__ ushort Xs[128][136];
    __shared__ ushort Ws[128][136];
    const int tid = threadIdx.x, row0 = blockIdx.x * 128;
    stage_x_f32_512(Xs, X, row0, N, tid);
    const int lane = tid & 63, w = tid >> 6, lr = lane & 15, g = lane >> 4;
    f32x4 acc[8];

    __syncthreads(); stage_w_512(Ws, W0, tid); __syncthreads();
#pragma unroll
    for (int j = 0; j < 8; ++j) acc[j] = (f32x4){0,0,0,0};
    mfma_core_512(Xs, Ws, acc, w, lr, g);
    store_bf16_512<1>(Y0, acc, b0, row0, w, lr, g, N);

    __syncthreads(); stage_w_512(Ws, W1, tid); __syncthreads();
#pragma unroll
    for (int j = 0; j < 8; ++j) acc[j] = (f32x4){0,0,0,0};
    mfma_core_512(Xs, Ws, acc, w, lr, g);
    store_bf16_512<0>(Y1, acc, nullptr, row0, w, lr, g, N);

    __syncthreads(); stage_w_512(Ws, W2, tid); __syncthreads();
#pragma unroll
    for (int j = 0; j < 8; ++j) acc[j] = (f32x4){0,0,0,0};
    mfma_core_512(Xs, Ws, acc, w, lr, g);
    store_bf16_512<0>(Y2, acc, b2, row0, w, lr, g, N);
}

// ---- attention triple (8-wave): X bf16 -> hg, K(sigmoid), V ----
__global__ __launch_bounds__(512, 2) void k_triple_attn(
    const ushort* __restrict__ X, const ushort* __restrict__ Wh, const ushort* __restrict__ Wk,
    const ushort* __restrict__ Wv, const float* __restrict__ bh, const float* __restrict__ bk,
    const float* __restrict__ bv, ushort* __restrict__ HG, ushort* __restrict__ K,
    ushort* __restrict__ V, int N)
{
    __shared__ ushort Xs[128][136];
    __shared__ ushort Ws[128][136];
    const int tid = threadIdx.x, row0 = blockIdx.x * 128;
    stage_x_bf16_512(Xs, X, row0, N, tid);
    const int lane = tid & 63, w = tid >> 6, lr = lane & 15, g = lane >> 4;
    f32x4 acc[8];

    __syncthreads(); stage_w_512(Ws, Wh, tid); __syncthreads();
#pragma unroll
    for (int j = 0; j < 8; ++j) acc[j] = (f32x4){0,0,0,0};
    mfma_core_512(Xs, Ws, acc, w, lr, g);
    store_bf16_512<0>(HG, acc, bh, row0, w, lr, g, N);

    __syncthreads(); stage_w_512(Ws, Wk, tid); __syncthreads();
#pragma unroll
    for (int j = 0; j < 8; ++j) acc[j] = (f32x4){0,0,0,0};
    mfma_core_512(Xs, Ws, acc, w, lr, g);
    store_bf16_512<2>(K, acc, bk, row0, w, lr, g, N);

    __syncthreads(); stage_w_512(Ws, Wv, tid); __syncthreads();
#pragma unroll
    for (int j = 0; j < 8; ++j) acc[j] = (f32x4){0,0,0,0};
    mfma_core_512(Xs, Ws, acc, w, lr, g);
    store_bf16_512<0>(V, acc, bv, row0, w, lr, g, N);
}

// ---- fused (8-wave): num GEMM + den + LN + *(hg+BETA) -> out GEMM [-> pred GEMM] ----
template <int LAST>
__global__ __launch_bounds__(512, 2) void k_fused_num_out(
    const ushort* __restrict__ K, const ushort* __restrict__ kvT,
    const float* __restrict__ ksum, const ushort* __restrict__ HG,
    const float* __restrict__ gam, const float* __restrict__ bet,
    const ushort* __restrict__ Wout, const float* __restrict__ bout,
    const ushort* __restrict__ predWt, const float* __restrict__ predb,
    ushort* __restrict__ Y, float* __restrict__ outp, int N)
{
    __shared__ ushort Xs[128][136];
    __shared__ ushort Ws[128][136];
    __shared__ float ks_lds[128], gam_s[128], bet_s[128], den_s[128];
    const int tid = threadIdx.x, row0 = blockIdx.x * 128;
    stage_x_bf16_512(Xs, K, row0, N, tid);
    if (tid < 128) { ks_lds[tid] = ksum[tid]; gam_s[tid] = gam[tid]; bet_s[tid] = bet[tid]; }
    stage_w_512(Ws, kvT, tid);
    const int lane = tid & 63, w = tid >> 6, lr = lane & 15, g = lane >> 4;
    f32x4 acc[8];
#pragma unroll
    for (int j = 0; j < 8; ++j) acc[j] = (f32x4){0,0,0,0};
    __syncthreads();

    float den0 = 0.f;
#pragma unroll
    for (int ks = 0; ks < 4; ++ks) {
        bf16x8 a0 = *reinterpret_cast<const bf16x8*>(&Xs[w * 16 + lr][ks * 32 + g * 8]);
#pragma unroll
        for (int cf = 0; cf < 8; ++cf) {
            bf16x8 bfr = *reinterpret_cast<const bf16x8*>(&Ws[cf * 16 + lr][ks * 32 + g * 8]);
            acc[cf] = __builtin_amdgcn_mfma_f32_16x16x32_bf16(a0, bfr, acc[cf], 0, 0, 0);
        }
#pragma unroll
        for (int e = 0; e < 8; ++e)
            den0 = fmaf(bf2f((ushort)a0[e]), ks_lds[ks * 32 + g * 8 + e], den0);
    }
    den0 += __shfl_xor(den0, 16, 64); den0 += __shfl_xor(den0, 32, 64);
    __syncthreads();
    if (lane < 16) den_s[w * 16 + lr] = den0;
    __syncthreads();

    {
        float inv[4];
#pragma unroll
        for (int j = 0; j < 4; ++j) inv[j] = 1.f / den_s[w * 16 + g * 4 + j];
#pragma unroll
        for (int cf = 0; cf < 8; ++cf)
#pragma unroll
            for (int j = 0; j < 4; ++j) acc[cf][j] *= inv[j];
#pragma unroll
        for (int j = 0; j < 4; ++j) {
            float s = 0.f, sq = 0.f;
#pragma unroll
            for (int cf = 0; cf < 8; ++cf) {
                float y = acc[cf][j];
                s += y; sq = fmaf(y, y, sq);
            }
#pragma unroll
            for (int off = 1; off < 16; off <<= 1) {
                s += __shfl_xor(s, off, 64); sq += __shfl_xor(sq, off, 64);
            }
            float mu = s * (1.f / 128.f);
            float var = sq * (1.f / 128.f) - mu * mu;
            float rs = rsqrtf(var + EPS);
            int rl = w * 16 + g * 4 + j;
            int rg = row0 + rl;
            if (rg < N) {
#pragma unroll
                for (int cf = 0; cf < 8; ++cf) {
                    int col = cf * 16 + lr;
                    float hgv = bf2f(HG[(size_t)rg * D + col]);
                    float o = ((acc[cf][j] - mu) * rs * gam_s[col] + bet_s[col]) * (hgv + BETA);
                    Xs[rl][col] = f2bf(o);
                }
            }
        }
    }
    stage_w_512(Ws, Wout, tid);
    __syncthreads();

#pragma unroll
    for (int j = 0; j < 8; ++j) acc[j] = (f32x4){0,0,0,0};
    mfma_core_512(Xs, Ws, acc, w, lr, g);

    if constexpr (LAST == 0) {
        store_bf16_512<1>(Y, acc, bout, row0, w, lr, g, N);
    } else {
        __syncthreads();
#pragma unroll
        for (int cf = 0; cf < 8; ++cf) {
            int col = cf * 16 + lr;
            float bb = bout[col];
#pragma unroll
            for (int j = 0; j < 4; ++j) {
                int rl = w * 16 + g * 4 + j;
                Xs[rl][col] = f2bf(fmaxf(acc[cf][j] + bb, 0.f));
            }
        }
#pragma unroll
        for (int p = 0; p < 2; ++p) {
            int idx = p * 512 + tid;
            if (idx < 48 * 16) {
                int r = idx >> 4, cc = idx & 15;
                ulonglong2 v = {0ull, 0ull};
                if (r < 40) v = *reinterpret_cast<const ulonglong2*>(predWt + (size_t)r * D + cc * 8);
                *reinterpret_cast<ulonglong2*>(&Ws[r][cc * 8]) = v;
            }
        }
        __syncthreads();
        f32x4 acc3[3];
#pragma unroll
        for (int j = 0; j < 3; ++j) acc3[j] = (f32x4){0,0,0,0};
#pragma unroll
        for (int ks = 0; ks < 4; ++ks) {
            bf16x8 a0 = *reinterpret_cast<const bf16x8*>(&Xs[w * 16 + lr][ks * 32 + g * 8]);
#pragma unroll
            for (int cf = 0; cf < 3; ++cf) {
                bf16x8 bfr = *reinterpret_cast<const bf16x8*>(&Ws[cf * 16 + lr][ks * 32 + g * 8]);
                acc3[cf] = __builtin_amdgcn_mfma_f32_16x16x32_bf16(a0, bfr, acc3[cf], 0, 0, 0);
            }
        }
#pragma unroll
        for (int cf = 0; cf < 3; ++cf) {
            int col = cf * 16 + lr;
            if (col < 40) {
                float bb = predb[col];
                int rg0 = row0 + w * 16 + g * 4;
                if (rg0 < N) {
#pragma unroll
                    for (int j = 0; j < 4; ++j)
                        outp[(size_t)(rg0 + j) * 40 + col] = acc3[cf][j] + bb;
                }
            }
        }
    }
}

// ---- kv via MFMA, grid-stride over 64-row tiles; KV_BLOCKS partials ----
__global__ __launch_bounds__(256, 2) void kv_mfma(
    const ushort* __restrict__ K, const ushort* __restrict__ V,
    float* __restrict__ kvp, float* __restrict__ ksump, int N)
{
    __shared__ ushort Kt[128][72];
    __shared__ ushort Vt[128][72];
    const int tid = threadIdx.x;
    const int lane = tid & 63, w = tid >> 6, lr = lane & 15, g = lane >> 4;
    f32x4 acc[2][8];
#pragma unroll
    for (int i = 0; i < 2; ++i) for (int j = 0; j < 8; ++j) acc[i][j] = (f32x4){0,0,0,0};
    float ksa0 = 0.f, ksa1 = 0.f;
    const int ntiles = (N + 63) / 64;

    for (int t = blockIdx.x; t < ntiles; t += gridDim.x) {
        int n0 = t * 64;
        __syncthreads();
#pragma unroll
        for (int it = 0; it < 8; ++it) {
            int idx = it * 256 + tid;
            int nl = idx >> 5, c4 = idx & 31;
            int rg = n0 + nl;
            ushort4 kvv = make_ushort4(0, 0, 0, 0);
            ushort4 vvv = make_ushort4(0, 0, 0, 0);
            if (rg < N) {
                kvv = *reinterpret_cast<const ushort4*>(K + (size_t)rg * D + c4 * 4);
                vvv = *reinterpret_cast<const ushort4*>(V + (size_t)rg * D + c4 * 4);
            }
            Kt[c4 * 4 + 0][nl] = kvv.x; Kt[c4 * 4 + 1][nl] = kvv.y;
            Kt[c4 * 4 + 2][nl] = kvv.z; Kt[c4 * 4 + 3][nl] = kvv.w;
            Vt[c4 * 4 + 0][nl] = vvv.x; Vt[c4 * 4 + 1][nl] = vvv.y;
            Vt[c4 * 4 + 2][nl] = vvv.z; Vt[c4 * 4 + 3][nl] = vvv.w;
        }
        __syncthreads();
#pragma unroll
        for (int ks = 0; ks < 2; ++ks) {
            bf16x8 a0 = *reinterpret_cast<const bf16x8*>(&Kt[w * 32 + lr][ks * 32 + g * 8]);
            bf16x8 a1 = *reinterpret_cast<const bf16x8*>(&Kt[w * 32 + 16 + lr][ks * 32 + g * 8]);
#pragma unroll
            for (int e = 0; e < 8; ++e) { ksa0 += bf2f((ushort)a0[e]); ksa1 += bf2f((ushort)a1[e]); }
#pragma unroll
            for (int cf = 0; cf < 8; ++cf) {
                bf16x8 bfr = *reinterpret_cast<const bf16x8*>(&Vt[cf * 16 + lr][ks * 32 + g * 8]);
                acc[0][cf] = __builtin_amdgcn_mfma_f32_16x16x32_bf16(a0, bfr, acc[0][cf], 0, 0, 0);
                acc[1][cf] = __builtin_amdgcn_mfma_f32_16x16x32_bf16(a1, bfr, acc[1][cf], 0, 0, 0);
            }
        }
    }
    ksa0 += __shfl_xor(ksa0, 16, 64); ksa0 += __shfl_xor(ksa0, 32, 64);
    ksa1 += __shfl_xor(ksa1, 16, 64); ksa1 += __shfl_xor(ksa1, 32, 64);
    if (lane < 16) {
        ksump[(size_t)blockIdx.x * D + w * 32 + lr] = ksa0;
        ksump[(size_t)blockIdx.x * D + w * 32 + 16 + lr] = ksa1;
    }
    float* kvb = kvp + (size_t)blockIdx.x * D * D;
#pragma unroll
    for (int cf = 0; cf < 8; ++cf) {
        int col = cf * 16 + lr;
#pragma unroll
        for (int rf = 0; rf < 2; ++rf)
#pragma unroll
            for (int j = 0; j < 4; ++j) {
                int d = w * 32 + rf * 16 + g * 4 + j;
                kvb[d * D + col] = acc[rf][cf][j];
            }
    }
}

// sum partials with 8-way ILP; emit kvT bf16 [m][d]; fold ksum (block 0)
__global__ void kv_finalize_T(const float* __restrict__ kvp, const float* __restrict__ ksump,
                              int nb, ushort* __restrict__ kvT, float* __restrict__ ksum) {
    int i = blockIdx.x * 256 + threadIdx.x;
    if (i < D * D) {
        float s0 = 0.f, s1 = 0.f, s2 = 0.f, s3 = 0.f, s4 = 0.f, s5 = 0.f, s6 = 0.f, s7 = 0.f;
        int p = 0;
        for (; p + 8 <= nb; p += 8) {
            s0 += kvp[(size_t)(p + 0) * (D * D) + i];
            s1 += kvp[(size_t)(p + 1) * (D * D) + i];
            s2 += kvp[(size_t)(p + 2) * (D * D) + i];
            s3 += kvp[(size_t)(p + 3) * (D * D) + i];
            s4 += kvp[(size_t)(p + 4) * (D * D) + i];
            s5 += kvp[(size_t)(p + 5) * (D * D) + i];
            s6 += kvp[(size_t)(p + 6) * (D * D) + i];
            s7 += kvp[(size_t)(p + 7) * (D * D) + i];
        }
        for (; p < nb; ++p) s0 += kvp[(size_t)p * (D * D) + i];
        float s = ((s0 + s1) + (s2 + s3)) + ((s4 + s5) + (s6 + s7));
        int d = i >> 7, m = i & 127;
        kvT[(size_t)m * D + d] = f2bf(s);
    }
    if (blockIdx.x == 0 && i < D) {
        float t0 = 0.f, t1 = 0.f, t2 = 0.f, t3 = 0.f;
        int p = 0;
        for (; p + 4 <= nb; p += 4) {
            t0 += ksump[(size_t)(p + 0) * D + i];
            t1 += ksump[(size_t)(p + 1) * D + i];
            t2 += ksump[(size_t)(p + 2) * D + i];
            t3 += ksump[(size_t)(p + 3) * D + i];
        }
        for (; p < nb; ++p) t0 += ksump[(size_t)p * D + i];
        ksum[i] = (t0 + t1) + (t2 + t3);
    }
}

// ---------- gather + stage1 epilogue, 2 waves per node ----------
// Wave pair (sub=0,1) splits the neighbor batches; partial (ax,ay) combined in LDS.
// Epilogue computed redundantly by both waves; store gated on sub==0.
__global__ __launch_bounds__(256) void gather_fused(
    const int* __restrict__ cnt, const int* __restrict__ bucket, const float* __restrict__ dinv,
    const ushort* __restrict__ xw, const ushort* __restrict__ base, const ushort* __restrict__ h,
    const float* __restrict__ gcn_b,
    const float* __restrict__ bn_mean, const float* __restrict__ bn_var,
    const float* __restrict__ bn_w, const float* __restrict__ bn_b,
    const float* __restrict__ ln0_g, const float* __restrict__ ln0_b,
    const float* __restrict__ lnf_g, const float* __restrict__ lnf_b,
    ushort* __restrict__ xg, int N)
{
    __shared__ float2 part[2][2][64];
    const int tid = threadIdx.x;
    const int p2 = tid >> 7;            // node slot in block (0,1)
    const int sub = (tid >> 6) & 1;     // neighbor-half (0,1)
    const int lane = tid & 63;
    int wid = blockIdx.x * 2 + p2;
    if (wid >= N) wid = N - 1;          // N even; defensive clamp (dup store benign)
    wid = __builtin_amdgcn_readfirstlane(wid);
    int m = cnt[wid]; m = m > LCAP ? LCAP : m;
    const int* bk = bucket + (size_t)wid * CAP;
    int c = lane * 2;
    float ax = 0.f, ay = 0.f;
    for (int i0 = sub * 8; i0 < m; i0 += 16) {
        int sA[8];
        float dA[8];
#pragma unroll
        for (int u = 0; u < 8; ++u)
            sA[u] = (i0 + u < m) ? bk[i0 + u] : 0;          // scalar loads
#pragma unroll
        for (int u = 0; u < 8; ++u)
            dA[u] = (i0 + u < m) ? dinv[sA[u]] : 0.f;       // scalar loads
#pragma unroll
        for (int u = 0; u < 8; ++u) {
            unsigned xv = *reinterpret_cast<const unsigned*>(xw + (size_t)sA[u] * D + c);
            ax = fmaf(dA[u], bf2f((ushort)xv), ax);
            ay = fmaf(dA[u], bf2f((ushort)(xv >> 16)), ay);
        }
    }
    part[p2][sub][lane] = make_float2(ax, ay);
    __syncthreads();
    ax = part[p2][0][lane].x + part[p2][1][lane].x;
    ay = part[p2][0][lane].y + part[p2][1][lane].y;

    float dn = dinv[wid];
    float dn2 = dn * dn;
    size_t off = (size_t)wid * D + c;
    unsigned xsv = *reinterpret_cast<const unsigned*>(xw + off);
    unsigned bsv = *reinterpret_cast<const unsigned*>(base + off);
    float2 gb = *reinterpret_cast<const float2*>(gcn_b + c);
    float2 bm = *reinterpret_cast<const float2*>(bn_mean + c);
    float2 bv = *reinterpret_cast<const float2*>(bn_var + c);
    float2 bw = *reinterpret_cast<const float2*>(bn_w + c);
    float2 bb = *reinterpret_cast<const float2*>(bn_b + c);
    float x10 = bf2f((ushort)bsv) + dn * ax + bf2f((ushort)xsv) * dn2 + gb.x;
    float x11 = bf2f((ushort)(bsv >> 16)) + dn * ay + bf2f((ushort)(xsv >> 16)) * dn2 + gb.y;
    x10 = (x10 - bm.x) * rsqrtf(bv.x + EPS) * bw.x + bb.x;
    x11 = (x11 - bm.y) * rsqrtf(bv.y + EPS) * bw.y + bb.y;
    x10 = fmaxf(x10, 0.f); x11 = fmaxf(x11, 0.f);
    unsigned hv = *reinterpret_cast<const unsigned*>(h + off);
    float t0 = bf2f((ushort)hv) * x10, t1 = bf2f((ushort)(hv >> 16)) * x11;
    float s = wave_allreduce_sum(t0 + t1);
    float sq = wave_allreduce_sum(t0 * t0 + t1 * t1);
    float mu = s * (1.f / 128.f);
    float var = sq * (1.f / 128.f) - mu * mu;
    float rs = rsqrtf(var + EPS);
    float2 g0 = *reinterpret_cast<const float2*>(ln0_g + c);
    float2 b0 = *reinterpret_cast<const float2*>(ln0_b + c);
    float xl0 = (1.0f - BETA) * ((t0 - mu) * rs * g0.x + b0.x) + BETA * x10;
    float xl1 = (1.0f - BETA) * ((t1 - mu) * rs * g0.y + b0.y) + BETA * x11;
    float s2 = wave_allreduce_sum(xl0 + xl1);
    float sq2 = wave_allreduce_sum(xl0 * xl0 + xl1 * xl1);
    float mu2 = s2 * (1.f / 128.f);
    float var2 = sq2 * (1.f / 128.f) - mu2 * mu2;
    float rs2 = rsqrtf(var2 + EPS);
    float2 gf = *reinterpret_cast<const float2*>(lnf_g + c);
    float2 bf = *reinterpret_cast<const float2*>(lnf_b + c);
    float o0 = (xl0 - mu2) * rs2 * gf.x + bf.x;
    float o1 = (xl1 - mu2) * rs2 * gf.y + bf.y;
    if (sub == 0)
        *reinterpret_cast<unsigned*>(xg + off) = packbf(o0, o1);
}

extern "C" void kernel_launch(void* const* d_in, const int* in_sizes, int n_in,
                              void* d_out, int out_size, void* d_ws, size_t ws_size,
                              hipStream_t stream)
{
    const float* x = (const float*)d_in[0];
    const int* ei = (const int*)d_in[1];
    const float* h_w = (const float*)d_in[2];
    const float* h_b = (const float*)d_in[3];
    const float* gcn_w = (const float*)d_in[4];
    const float* gcn_bv = (const float*)d_in[5];
    const float* lin_w = (const float*)d_in[6];
    const float* lin_b = (const float*)d_in[7];
    const float* bn_mean = (const float*)d_in[8];
    const float* bn_var = (const float*)d_in[9];
    const float* bn_w = (const float*)d_in[10];
    const float* bn_b = (const float*)d_in[11];
    const float* ln0_g = (const float*)d_in[12];
    const float* ln0_b = (const float*)d_in[13];
    const float* lnf_g = (const float*)d_in[14];
    const float* lnf_b = (const float*)d_in[15];
    const float* ga_h_w = (const float*)d_in[16];
    const float* ga_h_b = (const float*)d_in[17];
    const float* ga_k_w = (const float*)d_in[18];
    const float* ga_k_b = (const float*)d_in[19];
    const float* ga_v_w = (const float*)d_in[20];
    const float* ga_v_b = (const float*)d_in[21];
    const float* ga_ln_g = (const float*)d_in[22];
    const float* ga_ln_b = (const float*)d_in[23];
    const float* ga_out_w = (const float*)d_in[24];
    const float* ga_out_b = (const float*)d_in[25];
    const float* pred_w = (const float*)d_in[26];
    const float* pred_b = (const float*)d_in[27];
    float* out = (float*)d_out;

    const int N = in_sizes[0] / D;
    const int E = in_sizes[1] / 2;
    const int GL = in_sizes[17] / D;
    const int nbins = (N + (1 << BIN_SHIFT) - 1) >> BIN_SHIFT;   // 391 for N=100k

    // ---- workspace layout (all slab sizes multiples of 16 B) ----
    char* p = (char*)d_ws;
    int* cur = (int*)p;               p += (size_t)N * 4;
    float* dinv = (float*)p;          p += (size_t)N * 4;
    float* ksum = (float*)p;          p += 512;
    int* binCursor = (int*)p;         p += 2048;
    float* kvp = (float*)p;           p += (size_t)KV_BLOCKS * D * D * 4;
    float* ksump = (float*)p;         p += (size_t)KV_BLOCKS * D * 4;
    int* bucket = (int*)p;            p += (size_t)N * CAP * 4;
    int2* binned = (int2*)p;          p += (size_t)512 * BIN_CAPACITY * 8;
    ushort* Hb = (ushort*)p;          p += (size_t)N * D * 2;   // h / hg
    ushort* Kb = (ushort*)p;          p += (size_t)N * D * 2;   // xw / K
    ushort* Bs = (ushort*)p;          p += (size_t)N * D * 2;   // base
    ushort* Vb = (ushort*)p;          p += (size_t)N * D * 2;   // V
    ushort* X0 = (ushort*)p;          p += (size_t)N * D * 2;   // xg
    ushort* wt = (ushort*)p;          p += (size_t)10 * D * D * 2;
    ushort* kvT = (ushort*)p;         p += (size_t)D * D * 2;
    ushort* predWt = (ushort*)p;      p += (size_t)40 * D * 2;

    const int TPB = 256;
    const int gB = (N + 127) / 128;
    const int pairBlocks = (N + 1) / 2;

    hipMemsetAsync(binCursor, 0, 2048, stream);

    WP wp;
    wp.p[0] = h_w; wp.p[1] = gcn_w; wp.p[2] = lin_w;
    wp.p[3] = ga_h_w; wp.p[4] = ga_h_w + (size_t)D * D;
    wp.p[5] = ga_k_w; wp.p[6] = ga_k_w + (size_t)D * D;
    wp.p[7] = ga_v_w; wp.p[8] = ga_v_w + (size_t)D * D;
    wp.p[9] = ga_out_w;
    transpose_convert10<<<dim3(16, 10), TPB, 0, stream>>>(wp, wt);
    transpose_pred<<<20, TPB, 0, stream>>>(pred_w, predWt);

    // binned two-phase edge scatter: bins via streaming appends, buckets via LDS
    bin_edges<<<304, TPB, 0, stream>>>(ei, ei + E, E, nbins, binCursor, binned);
    bucket_from_bins_lds<<<nbins, TPB, 0, stream>>>(binned, binCursor, N, cur, dinv, bucket);

    k_triple1<<<gB, 512, 0, stream>>>(x, wt, wt + (size_t)D * D, wt + (size_t)2 * D * D,
                                      h_b, lin_b, Hb, Kb, Bs, N);
    gather_fused<<<pairBlocks, TPB, 0, stream>>>(cur, bucket, dinv, Kb, Bs, Hb, gcn_bv,
                                                 bn_mean, bn_var, bn_w, bn_b,
                                                 ln0_g, ln0_b, lnf_g, lnf_b, X0, N);

    for (int l = 0; l < GL; ++l) {
        k_triple_attn<<<gB, 512, 0, stream>>>(
            X0, wt + (size_t)(3 + l) * D * D, wt + (size_t)(5 + l) * D * D, wt + (size_t)(7 + l) * D * D,
            ga_h_b + l * D, ga_k_b + l * D, ga_v_b + l * D, Hb, Kb, Vb, N);
        kv_mfma<<<KV_BLOCKS, TPB, 0, stream>>>(Kb, Vb, kvp, ksump, N);
        kv_finalize_T<<<(D * D + 255) / 256, TPB, 0, stream>>>(kvp, ksump, KV_BLOCKS, kvT, ksum);
        if (l < GL - 1) {
            k_fused_num_out<0><<<gB, 512, 0, stream>>>(
                Kb, kvT, ksum, Hb, ga_ln_g + l * D, ga_ln_b + l * D,
                wt + (size_t)9 * D * D, ga_out_b, predWt, pred_b, X0, nullptr, N);
        } else {
            k_fused_num_out<1><<<gB, 512, 0, stream>>>(
                Kb, kvT, ksum, Hb, ga_ln_g + l * D, ga_ln_b + l * D,
                wt + (size_t)9 * D * D, ga_out_b, predWt, pred_b, X0, out, N);
        }
    }
}

// Round 21
// 503.853 us; speedup vs baseline: 1.1528x; 1.1528x over previous
//
#include <hip/hip_runtime.h>
#include <hip/hip_bf16.h>
#include <math.h>

constexpr int D = 128;
constexpr float EPS = 1e-5f;
constexpr float BETA = 0.9f;
constexpr int CAP = 64;        // global bucket row stride (ints)
constexpr int LCAP = 48;       // LDS bucket capacity (max in-degree ~45)
constexpr int KV_BLOCKS = 96;  // kv partial count (grid-stride)
constexpr int BIN_SHIFT = 8;   // 256 nodes per dst-bin
constexpr int BIN_CAPACITY = 5120;   // edges per bin region (mean 4096, +16 sigma slack)

typedef __attribute__((ext_vector_type(8))) short bf16x8;
typedef __attribute__((ext_vector_type(4))) float f32x4;

__device__ __forceinline__ float wave_allreduce_sum(float v) {
#pragma unroll
    for (int off = 32; off > 0; off >>= 1)
        v += __shfl_xor(v, off, 64);
    return v;
}

__device__ __forceinline__ ushort f2bf(float f) {
    union { float f; unsigned u; } v; v.f = f;
    unsigned r = v.u + 0x7FFFu + ((v.u >> 16) & 1u);   // RN-even
    return (ushort)(r >> 16);
}
__device__ __forceinline__ float bf2f(ushort u) {
    union { unsigned u; float f; } v; v.u = ((unsigned)u) << 16; return v.f;
}
__device__ __forceinline__ unsigned packbf(float a, float b) {
    return (unsigned)f2bf(a) | ((unsigned)f2bf(b) << 16);
}

template <int ACT> __device__ __forceinline__ float apply_act(float v) {
    if constexpr (ACT == 1) return fmaxf(v, 0.f);
    else if constexpr (ACT == 2) return 1.f / (1.f + expf(-v));
    else return v;
}

// ================= weight transpose+convert: W[k][n] f32 -> Wt[n][k] bf16 ==========
struct WP { const float* p[10]; };

__device__ __forceinline__ void transpose_tile_body(
    const float* __restrict__ src, ushort* __restrict__ d, float (*t)[33])
{
    int tr = (blockIdx.x >> 2) * 32, tc = (blockIdx.x & 3) * 32;
    int lr = threadIdx.x >> 5;
    int lc = threadIdx.x & 31;
#pragma unroll
    for (int i = 0; i < 4; ++i)
        t[lr + 8 * i][lc] = src[(size_t)(tr + lr + 8 * i) * D + tc + lc];
    __syncthreads();
#pragma unroll
    for (int i = 0; i < 4; ++i) {
        int r = lr + 8 * i;
        d[(size_t)(tc + r) * D + tr + lc] = f2bf(t[lc][r]);
    }
}

__global__ __launch_bounds__(256) void transpose_convert10(WP wp, ushort* __restrict__ dst) {
    __shared__ float t[32][33];
    transpose_tile_body(wp.p[blockIdx.y], dst + (size_t)blockIdx.y * D * D, t);
}

__global__ void transpose_pred(const float* __restrict__ w, ushort* __restrict__ wt) {
    int idx = blockIdx.x * 256 + threadIdx.x;   // 40*128
    if (idx < 40 * 128) {
        int n = idx >> 7, k = idx & 127;
        wt[idx] = f2bf(w[(size_t)k * 40 + n]);
    }
}

// ================= binned edge scatter (R16-validated; wider grid) =================
__global__ __launch_bounds__(256) void bin_edges(
    const int* __restrict__ esrc, const int* __restrict__ edst, int E, int nbins,
    int* __restrict__ binCursor, int2* __restrict__ binned)
{
    __shared__ int hist[512];
    __shared__ int base[512];
    const int tid = threadIdx.x;
    const int per = (E + gridDim.x - 1) / gridDim.x;
    const int e0 = blockIdx.x * per;
    const int e1 = min(e0 + per, E);
    for (int i = tid; i < nbins; i += 256) hist[i] = 0;
    __syncthreads();
    for (int e = e0 + tid; e < e1; e += 256)
        atomicAdd(&hist[edst[e] >> BIN_SHIFT], 1);
    __syncthreads();
    for (int i = tid; i < nbins; i += 256)
        base[i] = hist[i] ? atomicAdd(&binCursor[i], hist[i]) : 0;
    __syncthreads();
    for (int i = tid; i < nbins; i += 256) hist[i] = 0;   // reuse as running cursor
    __syncthreads();
    for (int e = e0 + tid; e < e1; e += 256) {
        int d = edst[e];
        int b = d >> BIN_SHIFT;
        int slot = base[b] + atomicAdd(&hist[b], 1);
        if (slot < BIN_CAPACITY)
            binned[(size_t)b * BIN_CAPACITY + slot] = make_int2(esrc[e], d);
    }
}

// Pass C: buckets assembled in LDS; streaming emit; also writes cnt and dinv.
__global__ __launch_bounds__(256, 2) void bucket_from_bins_lds(
    const int2* __restrict__ binned, const int* __restrict__ binCursor, int N,
    int* __restrict__ cur, float* __restrict__ dinv, int* __restrict__ bucket)
{
    __shared__ int lcnt[256];
    __shared__ int lbuck[256 * LCAP];
    const int b = blockIdx.x;
    const int tid = threadIdx.x;
    const int node0 = b << BIN_SHIFT;
    lcnt[tid] = 0;
    __syncthreads();
    int cnt = binCursor[b];
    if (cnt > BIN_CAPACITY) cnt = BIN_CAPACITY;
    const int2* src = binned + (size_t)b * BIN_CAPACITY;
    for (int i = tid; i < cnt; i += 256) {
        int2 e = src[i];
        int ln = e.y - node0;                  // 0..255
        int pos = atomicAdd(&lcnt[ln], 1);
        if (pos < LCAP) lbuck[ln * LCAP + pos] = e.x;
    }
    __syncthreads();
    int node = node0 + tid;
    if (node < N) {
        cur[node] = lcnt[tid];                 // raw degree
        dinv[node] = rsqrtf((float)(lcnt[tid] + 1));
    }
    for (int i = tid; i < 256 * CAP; i += 256) {
        int ln = i >> 6, slot = i & 63;
        int gnode = node0 + ln;
        if (gnode < N && slot < LCAP) {
            int c = lcnt[ln]; if (c > LCAP) c = LCAP;
            int lim = (c + 15) & ~15;          // whole 64B lines
            if (slot < lim)
                bucket[(size_t)gnode * CAP + slot] = lbuck[ln * LCAP + slot];
        }
    }
}

// ================= shared MFMA GEMM pieces =================
// 512-thread (8-wave) variants — wave w owns rows w*16..w*16+15
__device__ __forceinline__ void stage_x_f32_512(ushort (*Xs)[136], const float* __restrict__ X,
                                                int row0, int N, int tid) {
#pragma unroll
    for (int p = 0; p < 8; ++p) {
        int idx = p * 512 + tid;
        int r = idx >> 5, c4 = idx & 31;
        int rg = row0 + r;
        float4 v = make_float4(0.f, 0.f, 0.f, 0.f);
        if (rg < N) v = *reinterpret_cast<const float4*>(X + (size_t)rg * D + c4 * 4);
        ushort4 o; o.x = f2bf(v.x); o.y = f2bf(v.y); o.z = f2bf(v.z); o.w = f2bf(v.w);
        *reinterpret_cast<ushort4*>(&Xs[r][c4 * 4]) = o;
    }
}

__device__ __forceinline__ void stage_x_bf16_512(ushort (*Xs)[136], const ushort* __restrict__ X,
                                                 int row0, int N, int tid) {
#pragma unroll
    for (int p = 0; p < 4; ++p) {
        int idx = p * 512 + tid;
        int r = idx >> 4, c = idx & 15;
        int rg = row0 + r;
        ulonglong2 v = {0ull, 0ull};
        if (rg < N) v = *reinterpret_cast<const ulonglong2*>(X + (size_t)rg * D + c * 8);
        *reinterpret_cast<ulonglong2*>(&Xs[r][c * 8]) = v;
    }
}

__device__ __forceinline__ void stage_w_512(ushort (*Ws)[136], const ushort* __restrict__ Wt, int tid) {
#pragma unroll
    for (int p = 0; p < 4; ++p) {
        int idx = p * 512 + tid;
        int r = idx >> 4, c = idx & 15;
        *reinterpret_cast<ulonglong2*>(&Ws[r][c * 8]) =
            *reinterpret_cast<const ulonglong2*>(Wt + (size_t)r * D + c * 8);
    }
}

__device__ __forceinline__ void mfma_core_512(const ushort (*Xs)[136], const ushort (*Ws)[136],
                                              f32x4 (&acc)[8], int w, int lr, int g) {
#pragma unroll
    for (int ks = 0; ks < 4; ++ks) {
        bf16x8 a0 = *reinterpret_cast<const bf16x8*>(&Xs[w * 16 + lr][ks * 32 + g * 8]);
#pragma unroll
        for (int cf = 0; cf < 8; ++cf) {
            bf16x8 bfr = *reinterpret_cast<const bf16x8*>(&Ws[cf * 16 + lr][ks * 32 + g * 8]);
            acc[cf] = __builtin_amdgcn_mfma_f32_16x16x32_bf16(a0, bfr, acc[cf], 0, 0, 0);
        }
    }
}

template <int ACT>
__device__ __forceinline__ void store_bf16_512(ushort* __restrict__ Y, const f32x4 (&acc)[8],
    const float* __restrict__ bias, int row0, int w, int lr, int g, int N) {
#pragma unroll
    for (int cf = 0; cf < 8; ++cf) {
        int col = cf * 16 + lr;
        float bb = bias ? bias[col] : 0.f;
        int rg0 = row0 + w * 16 + g * 4;
        if (rg0 < N) {           // N%4==0: whole 4-row group valid when rg0<N
#pragma unroll
            for (int j = 0; j < 4; ++j)
                Y[(size_t)(rg0 + j) * D + col] = f2bf(apply_act<ACT>(acc[cf][j] + bb));
        }
    }
}

// ---- stage1 triple (pure GEMM, 8-wave) ----
__global__ __launch_bounds__(512, 2) void k_triple1(
    const float* __restrict__ X, const ushort* __restrict__ W0, const ushort* __restrict__ W1,
    const ushort* __restrict__ W2, const float* __restrict__ b0, const float* __restrict__ b2,
    ushort* __restrict__ Y0, ushort* __restrict__ Y1, ushort* __restrict__ Y2, int N)
{
    __shared__ ushort Xs[128][136];
    __shared__ ushort Ws[128][136];
    const int tid = threadIdx.x, row0 = blockIdx.x * 128;
    stage_x_f32_512(Xs, X, row0, N, tid);
    const int lane = tid & 63, w = tid >> 6, lr = lane & 15, g = lane >> 4;
    f32x4 acc[8];

    __syncthreads(); stage_w_512(Ws, W0, tid); __syncthreads();
#pragma unroll
    for (int j = 0; j < 8; ++j) acc[j] = (f32x4){0,0,0,0};
    mfma_core_512(Xs, Ws, acc, w, lr, g);
    store_bf16_512<1>(Y0, acc, b0, row0, w, lr, g, N);

    __syncthreads(); stage_w_512(Ws, W1, tid); __syncthreads();
#pragma unroll
    for (int j = 0; j < 8; ++j) acc[j] = (f32x4){0,0,0,0};
    mfma_core_512(Xs, Ws, acc, w, lr, g);
    store_bf16_512<0>(Y1, acc, nullptr, row0, w, lr, g, N);

    __syncthreads(); stage_w_512(Ws, W2, tid); __syncthreads();
#pragma unroll
    for (int j = 0; j < 8; ++j) acc[j] = (f32x4){0,0,0,0};
    mfma_core_512(Xs, Ws, acc, w, lr, g);
    store_bf16_512<0>(Y2, acc, b2, row0, w, lr, g, N);
}

// ---- attention triple (8-wave): X bf16 -> hg, K(sigmoid), V ----
__global__ __launch_bounds__(512, 2) void k_triple_attn(
    const ushort* __restrict__ X, const ushort* __restrict__ Wh, const ushort* __restrict__ Wk,
    const ushort* __restrict__ Wv, const float* __restrict__ bh, const float* __restrict__ bk,
    const float* __restrict__ bv, ushort* __restrict__ HG, ushort* __restrict__ K,
    ushort* __restrict__ V, int N)
{
    __shared__ ushort Xs[128][136];
    __shared__ ushort Ws[128][136];
    const int tid = threadIdx.x, row0 = blockIdx.x * 128;
    stage_x_bf16_512(Xs, X, row0, N, tid);
    const int lane = tid & 63, w = tid >> 6, lr = lane & 15, g = lane >> 4;
    f32x4 acc[8];

    __syncthreads(); stage_w_512(Ws, Wh, tid); __syncthreads();
#pragma unroll
    for (int j = 0; j < 8; ++j) acc[j] = (f32x4){0,0,0,0};
    mfma_core_512(Xs, Ws, acc, w, lr, g);
    store_bf16_512<0>(HG, acc, bh, row0, w, lr, g, N);

    __syncthreads(); stage_w_512(Ws, Wk, tid); __syncthreads();
#pragma unroll
    for (int j = 0; j < 8; ++j) acc[j] = (f32x4){0,0,0,0};
    mfma_core_512(Xs, Ws, acc, w, lr, g);
    store_bf16_512<2>(K, acc, bk, row0, w, lr, g, N);

    __syncthreads(); stage_w_512(Ws, Wv, tid); __syncthreads();
#pragma unroll
    for (int j = 0; j < 8; ++j) acc[j] = (f32x4){0,0,0,0};
    mfma_core_512(Xs, Ws, acc, w, lr, g);
    store_bf16_512<0>(V, acc, bv, row0, w, lr, g, N);
}

// ---- fused (8-wave): num GEMM + den + LN + *(hg+BETA) -> out GEMM [-> pred GEMM] ----
template <int LAST>
__global__ __launch_bounds__(512, 2) void k_fused_num_out(
    const ushort* __restrict__ K, const ushort* __restrict__ kvT,
    const float* __restrict__ ksum, const ushort* __restrict__ HG,
    const float* __restrict__ gam, const float* __restrict__ bet,
    const ushort* __restrict__ Wout, const float* __restrict__ bout,
    const ushort* __restrict__ predWt, const float* __restrict__ predb,
    ushort* __restrict__ Y, float* __restrict__ outp, int N)
{
    __shared__ ushort Xs[128][136];
    __shared__ ushort Ws[128][136];
    __shared__ float ks_lds[128], gam_s[128], bet_s[128], den_s[128];
    const int tid = threadIdx.x, row0 = blockIdx.x * 128;
    stage_x_bf16_512(Xs, K, row0, N, tid);
    if (tid < 128) { ks_lds[tid] = ksum[tid]; gam_s[tid] = gam[tid]; bet_s[tid] = bet[tid]; }
    stage_w_512(Ws, kvT, tid);
    const int lane = tid & 63, w = tid >> 6, lr = lane & 15, g = lane >> 4;
    f32x4 acc[8];
#pragma unroll
    for (int j = 0; j < 8; ++j) acc[j] = (f32x4){0,0,0,0};
    __syncthreads();

    float den0 = 0.f;
#pragma unroll
    for (int ks = 0; ks < 4; ++ks) {
        bf16x8 a0 = *reinterpret_cast<const bf16x8*>(&Xs[w * 16 + lr][ks * 32 + g * 8]);
#pragma unroll
        for (int cf = 0; cf < 8; ++cf) {
            bf16x8 bfr = *reinterpret_cast<const bf16x8*>(&Ws[cf * 16 + lr][ks * 32 + g * 8]);
            acc[cf] = __builtin_amdgcn_mfma_f32_16x16x32_bf16(a0, bfr, acc[cf], 0, 0, 0);
        }
#pragma unroll
        for (int e = 0; e < 8; ++e)
            den0 = fmaf(bf2f((ushort)a0[e]), ks_lds[ks * 32 + g * 8 + e], den0);
    }
    den0 += __shfl_xor(den0, 16, 64); den0 += __shfl_xor(den0, 32, 64);
    __syncthreads();
    if (lane < 16) den_s[w * 16 + lr] = den0;
    __syncthreads();

    {
        float inv[4];
#pragma unroll
        for (int j = 0; j < 4; ++j) inv[j] = 1.f / den_s[w * 16 + g * 4 + j];
#pragma unroll
        for (int cf = 0; cf < 8; ++cf)
#pragma unroll
            for (int j = 0; j < 4; ++j) acc[cf][j] *= inv[j];
#pragma unroll
        for (int j = 0; j < 4; ++j) {
            float s = 0.f, sq = 0.f;
#pragma unroll
            for (int cf = 0; cf < 8; ++cf) {
                float y = acc[cf][j];
                s += y; sq = fmaf(y, y, sq);
            }
#pragma unroll
            for (int off = 1; off < 16; off <<= 1) {
                s += __shfl_xor(s, off, 64); sq += __shfl_xor(sq, off, 64);
            }
            float mu = s * (1.f / 128.f);
            float var = sq * (1.f / 128.f) - mu * mu;
            float rs = rsqrtf(var + EPS);
            int rl = w * 16 + g * 4 + j;
            int rg = row0 + rl;
            if (rg < N) {
#pragma unroll
                for (int cf = 0; cf < 8; ++cf) {
                    int col = cf * 16 + lr;
                    float hgv = bf2f(HG[(size_t)rg * D + col]);
                    float o = ((acc[cf][j] - mu) * rs * gam_s[col] + bet_s[col]) * (hgv + BETA);
                    Xs[rl][col] = f2bf(o);
                }
            }
        }
    }
    stage_w_512(Ws, Wout, tid);
    __syncthreads();

#pragma unroll
    for (int j = 0; j < 8; ++j) acc[j] = (f32x4){0,0,0,0};
    mfma_core_512(Xs, Ws, acc, w, lr, g);

    if constexpr (LAST == 0) {
        store_bf16_512<1>(Y, acc, bout, row0, w, lr, g, N);
    } else {
        __syncthreads();
#pragma unroll
        for (int cf = 0; cf < 8; ++cf) {
            int col = cf * 16 + lr;
            float bb = bout[col];
#pragma unroll
            for (int j = 0; j < 4; ++j) {
                int rl = w * 16 + g * 4 + j;
                Xs[rl][col] = f2bf(fmaxf(acc[cf][j] + bb, 0.f));
            }
        }
#pragma unroll
        for (int p = 0; p < 2; ++p) {
            int idx = p * 512 + tid;
            if (idx < 48 * 16) {
                int r = idx >> 4, cc = idx & 15;
                ulonglong2 v = {0ull, 0ull};
                if (r < 40) v = *reinterpret_cast<const ulonglong2*>(predWt + (size_t)r * D + cc * 8);
                *reinterpret_cast<ulonglong2*>(&Ws[r][cc * 8]) = v;
            }
        }
        __syncthreads();
        f32x4 acc3[3];
#pragma unroll
        for (int j = 0; j < 3; ++j) acc3[j] = (f32x4){0,0,0,0};
#pragma unroll
        for (int ks = 0; ks < 4; ++ks) {
            bf16x8 a0 = *reinterpret_cast<const bf16x8*>(&Xs[w * 16 + lr][ks * 32 + g * 8]);
#pragma unroll
            for (int cf = 0; cf < 3; ++cf) {
                bf16x8 bfr = *reinterpret_cast<const bf16x8*>(&Ws[cf * 16 + lr][ks * 32 + g * 8]);
                acc3[cf] = __builtin_amdgcn_mfma_f32_16x16x32_bf16(a0, bfr, acc3[cf], 0, 0, 0);
            }
        }
#pragma unroll
        for (int cf = 0; cf < 3; ++cf) {
            int col = cf * 16 + lr;
            if (col < 40) {
                float bb = predb[col];
                int rg0 = row0 + w * 16 + g * 4;
                if (rg0 < N) {
#pragma unroll
                    for (int j = 0; j < 4; ++j)
                        outp[(size_t)(rg0 + j) * 40 + col] = acc3[cf][j] + bb;
                }
            }
        }
    }
}

// ---- kv via MFMA, grid-stride over 64-row tiles; KV_BLOCKS partials ----
__global__ __launch_bounds__(256, 2) void kv_mfma(
    const ushort* __restrict__ K, const ushort* __restrict__ V,
    float* __restrict__ kvp, float* __restrict__ ksump, int N)
{
    __shared__ ushort Kt[128][72];
    __shared__ ushort Vt[128][72];
    const int tid = threadIdx.x;
    const int lane = tid & 63, w = tid >> 6, lr = lane & 15, g = lane >> 4;
    f32x4 acc[2][8];
#pragma unroll
    for (int i = 0; i < 2; ++i) for (int j = 0; j < 8; ++j) acc[i][j] = (f32x4){0,0,0,0};
    float ksa0 = 0.f, ksa1 = 0.f;
    const int ntiles = (N + 63) / 64;

    for (int t = blockIdx.x; t < ntiles; t += gridDim.x) {
        int n0 = t * 64;
        __syncthreads();
#pragma unroll
        for (int it = 0; it < 8; ++it) {
            int idx = it * 256 + tid;
            int nl = idx >> 5, c4 = idx & 31;
            int rg = n0 + nl;
            ushort4 kvv = make_ushort4(0, 0, 0, 0);
            ushort4 vvv = make_ushort4(0, 0, 0, 0);
            if (rg < N) {
                kvv = *reinterpret_cast<const ushort4*>(K + (size_t)rg * D + c4 * 4);
                vvv = *reinterpret_cast<const ushort4*>(V + (size_t)rg * D + c4 * 4);
            }
            Kt[c4 * 4 + 0][nl] = kvv.x; Kt[c4 * 4 + 1][nl] = kvv.y;
            Kt[c4 * 4 + 2][nl] = kvv.z; Kt[c4 * 4 + 3][nl] = kvv.w;
            Vt[c4 * 4 + 0][nl] = vvv.x; Vt[c4 * 4 + 1][nl] = vvv.y;
            Vt[c4 * 4 + 2][nl] = vvv.z; Vt[c4 * 4 + 3][nl] = vvv.w;
        }
        __syncthreads();
#pragma unroll
        for (int ks = 0; ks < 2; ++ks) {
            bf16x8 a0 = *reinterpret_cast<const bf16x8*>(&Kt[w * 32 + lr][ks * 32 + g * 8]);
            bf16x8 a1 = *reinterpret_cast<const bf16x8*>(&Kt[w * 32 + 16 + lr][ks * 32 + g * 8]);
#pragma unroll
            for (int e = 0; e < 8; ++e) { ksa0 += bf2f((ushort)a0[e]); ksa1 += bf2f((ushort)a1[e]); }
#pragma unroll
            for (int cf = 0; cf < 8; ++cf) {
                bf16x8 bfr = *reinterpret_cast<const bf16x8*>(&Vt[cf * 16 + lr][ks * 32 + g * 8]);
                acc[0][cf] = __builtin_amdgcn_mfma_f32_16x16x32_bf16(a0, bfr, acc[0][cf], 0, 0, 0);
                acc[1][cf] = __builtin_amdgcn_mfma_f32_16x16x32_bf16(a1, bfr, acc[1][cf], 0, 0, 0);
            }
        }
    }
    ksa0 += __shfl_xor(ksa0, 16, 64); ksa0 += __shfl_xor(ksa0, 32, 64);
    ksa1 += __shfl_xor(ksa1, 16, 64); ksa1 += __shfl_xor(ksa1, 32, 64);
    if (lane < 16) {
        ksump[(size_t)blockIdx.x * D + w * 32 + lr] = ksa0;
        ksump[(size_t)blockIdx.x * D + w * 32 + 16 + lr] = ksa1;
    }
    float* kvb = kvp + (size_t)blockIdx.x * D * D;
#pragma unroll
    for (int cf = 0; cf < 8; ++cf) {
        int col = cf * 16 + lr;
#pragma unroll
        for (int rf = 0; rf < 2; ++rf)
#pragma unroll
            for (int j = 0; j < 4; ++j) {
                int d = w * 32 + rf * 16 + g * 4 + j;
                kvb[d * D + col] = acc[rf][cf][j];
            }
    }
}

// sum partials with 8-way ILP; emit kvT bf16 [m][d]; fold ksum (block 0)
__global__ void kv_finalize_T(const float* __restrict__ kvp, const float* __restrict__ ksump,
                              int nb, ushort* __restrict__ kvT, float* __restrict__ ksum) {
    int i = blockIdx.x * 256 + threadIdx.x;
    if (i < D * D) {
        float s0 = 0.f, s1 = 0.f, s2 = 0.f, s3 = 0.f, s4 = 0.f, s5 = 0.f, s6 = 0.f, s7 = 0.f;
        int p = 0;
        for (; p + 8 <= nb; p += 8) {
            s0 += kvp[(size_t)(p + 0) * (D * D) + i];
            s1 += kvp[(size_t)(p + 1) * (D * D) + i];
            s2 += kvp[(size_t)(p + 2) * (D * D) + i];
            s3 += kvp[(size_t)(p + 3) * (D * D) + i];
            s4 += kvp[(size_t)(p + 4) * (D * D) + i];
            s5 += kvp[(size_t)(p + 5) * (D * D) + i];
            s6 += kvp[(size_t)(p + 6) * (D * D) + i];
            s7 += kvp[(size_t)(p + 7) * (D * D) + i];
        }
        for (; p < nb; ++p) s0 += kvp[(size_t)p * (D * D) + i];
        float s = ((s0 + s1) + (s2 + s3)) + ((s4 + s5) + (s6 + s7));
        int d = i >> 7, m = i & 127;
        kvT[(size_t)m * D + d] = f2bf(s);
    }
    if (blockIdx.x == 0 && i < D) {
        float t0 = 0.f, t1 = 0.f, t2 = 0.f, t3 = 0.f;
        int p = 0;
        for (; p + 4 <= nb; p += 4) {
            t0 += ksump[(size_t)(p + 0) * D + i];
            t1 += ksump[(size_t)(p + 1) * D + i];
            t2 += ksump[(size_t)(p + 2) * D + i];
            t3 += ksump[(size_t)(p + 3) * D + i];
        }
        for (; p < nb; ++p) t0 += ksump[(size_t)p * D + i];
        ksum[i] = (t0 + t1) + (t2 + t3);
    }
}

// ---------- gather + stage1 epilogue fused (R18/R19-validated: 1 wave/node, scalarized) ----------
__global__ __launch_bounds__(256) void gather_fused(
    const int* __restrict__ cnt, const int* __restrict__ bucket, const float* __restrict__ dinv,
    const ushort* __restrict__ xw, const ushort* __restrict__ base, const ushort* __restrict__ h,
    const float* __restrict__ gcn_b,
    const float* __restrict__ bn_mean, const float* __restrict__ bn_var,
    const float* __restrict__ bn_w, const float* __restrict__ bn_b,
    const float* __restrict__ ln0_g, const float* __restrict__ ln0_b,
    const float* __restrict__ lnf_g, const float* __restrict__ lnf_b,
    ushort* __restrict__ xg, int N)
{
    int wid = __builtin_amdgcn_readfirstlane(blockIdx.x * 4 + (threadIdx.x >> 6));
    int lane = threadIdx.x & 63;
    if (wid >= N) return;
    int m = cnt[wid]; m = m > LCAP ? LCAP : m;
    const int* bk = bucket + (size_t)wid * CAP;
    int c = lane * 2;
    float ax = 0.f, ay = 0.f;
    for (int i0 = 0; i0 < m; i0 += 8) {
        int sA[8];
        float dA[8];
#pragma unroll
        for (int u = 0; u < 8; ++u)
            sA[u] = (i0 + u < m) ? bk[i0 + u] : 0;          // scalar loads, 8 in flight
#pragma unroll
        for (int u = 0; u < 8; ++u)
            dA[u] = (i0 + u < m) ? dinv[sA[u]] : 0.f;       // scalar loads, 8 in flight
#pragma unroll
        for (int u = 0; u < 8; ++u) {
            unsigned xv = *reinterpret_cast<const unsigned*>(xw + (size_t)sA[u] * D + c);
            ax = fmaf(dA[u], bf2f((ushort)xv), ax);
            ay = fmaf(dA[u], bf2f((ushort)(xv >> 16)), ay);
        }
    }
    float dn = dinv[wid];
    float dn2 = dn * dn;
    size_t off = (size_t)wid * D + c;
    unsigned xsv = *reinterpret_cast<const unsigned*>(xw + off);
    unsigned bsv = *reinterpret_cast<const unsigned*>(base + off);
    float2 gb = *reinterpret_cast<const float2*>(gcn_b + c);
    float2 bm = *reinterpret_cast<const float2*>(bn_mean + c);
    float2 bv = *reinterpret_cast<const float2*>(bn_var + c);
    float2 bw = *reinterpret_cast<const float2*>(bn_w + c);
    float2 bb = *reinterpret_cast<const float2*>(bn_b + c);
    float x10 = bf2f((ushort)bsv) + dn * ax + bf2f((ushort)xsv) * dn2 + gb.x;
    float x11 = bf2f((ushort)(bsv >> 16)) + dn * ay + bf2f((ushort)(xsv >> 16)) * dn2 + gb.y;
    x10 = (x10 - bm.x) * rsqrtf(bv.x + EPS) * bw.x + bb.x;
    x11 = (x11 - bm.y) * rsqrtf(bv.y + EPS) * bw.y + bb.y;
    x10 = fmaxf(x10, 0.f); x11 = fmaxf(x11, 0.f);
    unsigned hv = *reinterpret_cast<const unsigned*>(h + off);
    float t0 = bf2f((ushort)hv) * x10, t1 = bf2f((ushort)(hv >> 16)) * x11;
    float s = wave_allreduce_sum(t0 + t1);
    float sq = wave_allreduce_sum(t0 * t0 + t1 * t1);
    float mu = s * (1.f / 128.f);
    float var = sq * (1.f / 128.f) - mu * mu;
    float rs = rsqrtf(var + EPS);
    float2 g0 = *reinterpret_cast<const float2*>(ln0_g + c);
    float2 b0 = *reinterpret_cast<const float2*>(ln0_b + c);
    float xl0 = (1.0f - BETA) * ((t0 - mu) * rs * g0.x + b0.x) + BETA * x10;
    float xl1 = (1.0f - BETA) * ((t1 - mu) * rs * g0.y + b0.y) + BETA * x11;
    float s2 = wave_allreduce_sum(xl0 + xl1);
    float sq2 = wave_allreduce_sum(xl0 * xl0 + xl1 * xl1);
    float mu2 = s2 * (1.f / 128.f);
    float var2 = sq2 * (1.f / 128.f) - mu2 * mu2;
    float rs2 = rsqrtf(var2 + EPS);
    float2 gf = *reinterpret_cast<const float2*>(lnf_g + c);
    float2 bf = *reinterpret_cast<const float2*>(lnf_b + c);
    float o0 = (xl0 - mu2) * rs2 * gf.x + bf.x;
    float o1 = (xl1 - mu2) * rs2 * gf.y + bf.y;
    *reinterpret_cast<unsigned*>(xg + off) = packbf(o0, o1);
}

extern "C" void kernel_launch(void* const* d_in, const int* in_sizes, int n_in,
                              void* d_out, int out_size, void* d_ws, size_t ws_size,
                              hipStream_t stream)
{
    const float* x = (const float*)d_in[0];
    const int* ei = (const int*)d_in[1];
    const float* h_w = (const float*)d_in[2];
    const float* h_b = (const float*)d_in[3];
    const float* gcn_w = (const float*)d_in[4];
    const float* gcn_bv = (const float*)d_in[5];
    const float* lin_w = (const float*)d_in[6];
    const float* lin_b = (const float*)d_in[7];
    const float* bn_mean = (const float*)d_in[8];
    const float* bn_var = (const float*)d_in[9];
    const float* bn_w = (const float*)d_in[10];
    const float* bn_b = (const float*)d_in[11];
    const float* ln0_g = (const float*)d_in[12];
    const float* ln0_b = (const float*)d_in[13];
    const float* lnf_g = (const float*)d_in[14];
    const float* lnf_b = (const float*)d_in[15];
    const float* ga_h_w = (const float*)d_in[16];
    const float* ga_h_b = (const float*)d_in[17];
    const float* ga_k_w = (const float*)d_in[18];
    const float* ga_k_b = (const float*)d_in[19];
    const float* ga_v_w = (const float*)d_in[20];
    const float* ga_v_b = (const float*)d_in[21];
    const float* ga_ln_g = (const float*)d_in[22];
    const float* ga_ln_b = (const float*)d_in[23];
    const float* ga_out_w = (const float*)d_in[24];
    const float* ga_out_b = (const float*)d_in[25];
    const float* pred_w = (const float*)d_in[26];
    const float* pred_b = (const float*)d_in[27];
    float* out = (float*)d_out;

    const int N = in_sizes[0] / D;
    const int E = in_sizes[1] / 2;
    const int GL = in_sizes[17] / D;
    const int nbins = (N + (1 << BIN_SHIFT) - 1) >> BIN_SHIFT;   // 391 for N=100k

    // ---- workspace layout (all slab sizes multiples of 16 B) ----
    char* p = (char*)d_ws;
    int* cur = (int*)p;               p += (size_t)N * 4;
    float* dinv = (float*)p;          p += (size_t)N * 4;
    float* ksum = (float*)p;          p += 512;
    int* binCursor = (int*)p;         p += 2048;
    float* kvp = (float*)p;           p += (size_t)KV_BLOCKS * D * D * 4;
    float* ksump = (float*)p;         p += (size_t)KV_BLOCKS * D * 4;
    int* bucket = (int*)p;            p += (size_t)N * CAP * 4;
    int2* binned = (int2*)p;          p += (size_t)512 * BIN_CAPACITY * 8;
    ushort* Hb = (ushort*)p;          p += (size_t)N * D * 2;   // h / hg
    ushort* Kb = (ushort*)p;          p += (size_t)N * D * 2;   // xw / K
    ushort* Bs = (ushort*)p;          p += (size_t)N * D * 2;   // base
    ushort* Vb = (ushort*)p;          p += (size_t)N * D * 2;   // V
    ushort* X0 = (ushort*)p;          p += (size_t)N * D * 2;   // xg
    ushort* wt = (ushort*)p;          p += (size_t)10 * D * D * 2;
    ushort* kvT = (ushort*)p;         p += (size_t)D * D * 2;
    ushort* predWt = (ushort*)p;      p += (size_t)40 * D * 2;

    const int TPB = 256;
    const int gB = (N + 127) / 128;
    const int rowBlocks = (N + 3) / 4;

    hipMemsetAsync(binCursor, 0, 2048, stream);

    WP wp;
    wp.p[0] = h_w; wp.p[1] = gcn_w; wp.p[2] = lin_w;
    wp.p[3] = ga_h_w; wp.p[4] = ga_h_w + (size_t)D * D;
    wp.p[5] = ga_k_w; wp.p[6] = ga_k_w + (size_t)D * D;
    wp.p[7] = ga_v_w; wp.p[8] = ga_v_w + (size_t)D * D;
    wp.p[9] = ga_out_w;
    transpose_convert10<<<dim3(16, 10), TPB, 0, stream>>>(wp, wt);
    transpose_pred<<<20, TPB, 0, stream>>>(pred_w, predWt);

    // binned two-phase edge scatter: bins via streaming appends, buckets via LDS
    bin_edges<<<608, TPB, 0, stream>>>(ei, ei + E, E, nbins, binCursor, binned);
    bucket_from_bins_lds<<<nbins, TPB, 0, stream>>>(binned, binCursor, N, cur, dinv, bucket);

    k_triple1<<<gB, 512, 0, stream>>>(x, wt, wt + (size_t)D * D, wt + (size_t)2 * D * D,
                                      h_b, lin_b, Hb, Kb, Bs, N);
    gather_fused<<<rowBlocks, TPB, 0, stream>>>(cur, bucket, dinv, Kb, Bs, Hb, gcn_bv,
                                                bn_mean, bn_var, bn_w, bn_b,
                                                ln0_g, ln0_b, lnf_g, lnf_b, X0, N);

    for (int l = 0; l < GL; ++l) {
        k_triple_attn<<<gB, 512, 0, stream>>>(
            X0, wt + (size_t)(3 + l) * D * D, wt + (size_t)(5 + l) * D * D, wt + (size_t)(7 + l) * D * D,
            ga_h_b + l * D, ga_k_b + l * D, ga_v_b + l * D, Hb, Kb, Vb, N);
        kv_mfma<<<KV_BLOCKS, TPB, 0, stream>>>(Kb, Vb, kvp, ksump, N);
        kv_finalize_T<<<(D * D + 255) / 256, TPB, 0, stream>>>(kvp, ksump, KV_BLOCKS, kvT, ksum);
        if (l < GL - 1) {
            k_fused_num_out<0><<<gB, 512, 0, stream>>>(
                Kb, kvT, ksum, Hb, ga_ln_g + l * D, ga_ln_b + l * D,
                wt + (size_t)9 * D * D, ga_out_b, predWt, pred_b, X0, nullptr, N);
        } else {
            k_fused_num_out<1><<<gB, 512, 0, stream>>>(
                Kb, kvT, ksum, Hb, ga_ln_g + l * D, ga_ln_b + l * D,
                wt + (size_t)9 * D * D, ga_out_b, predWt, pred_b, X0, out, N);
        }
    }
}